// Round 16
// baseline (133.709 us; speedup 1.0000x reference)
//
#include <hip/hip_runtime.h>
#include <hip/hip_bf16.h>
#include <math.h>

#define T_DIM 2048
#define E_DIM 1536
#define K_DIM 1536

typedef unsigned short u16;
typedef unsigned int u32;
typedef __attribute__((ext_vector_type(8))) short bf16x8;
typedef __attribute__((ext_vector_type(4))) float f32x4;

__device__ __forceinline__ u16 f2bf(float x) {
    unsigned u = __float_as_uint(x);
    return (u16)((u + 0x7fffu + ((u >> 16) & 1u)) >> 16);
}

#define GLOAD16(gsrc, ldst)                                                              \
    __builtin_amdgcn_global_load_lds((const __attribute__((address_space(1))) u32*)(gsrc), \
                                     (__attribute__((address_space(3))) u32*)(ldst), 16, 0, 0)

// ---------------- all f32 -> bf16 conversions in ONE kernel (5 segments)
__global__ __launch_bounds__(256) void cvt_bf16_5(const float* __restrict__ s0, u16* __restrict__ d0,
                                                  const float* __restrict__ s1, u16* __restrict__ d1,
                                                  const float* __restrict__ s2, u16* __restrict__ d2,
                                                  const float* __restrict__ s3, u16* __restrict__ d3,
                                                  const float* __restrict__ s4, u16* __restrict__ d4) {
    int i = blockIdx.x * 256 + threadIdx.x;
    const float* s;
    u16* d;
    int off;
    if (i < 786432)       { s = s0; d = d0; off = i; }
    else if (i < 1376256) { s = s1; d = d1; off = i - 786432; }
    else if (i < 1671168) { s = s2; d = d2; off = i - 1376256; }
    else if (i < 1966080) { s = s3; d = d3; off = i - 1671168; }
    else                  { s = s4; d = d4; off = i - 1966080; }
    float4 v = ((const float4*)s)[off];
    ((ushort4*)d)[off] = make_ushort4(f2bf(v.x), f2bf(v.y), f2bf(v.z), f2bf(v.w));
}

// ---------------- fused QKV GEMM, 128x128 tile, RoPE/pack epilogue (unchanged)
__global__ __launch_bounds__(256) void gemm_qkv_fused(const u16* __restrict__ A,
                                                      const u16* __restrict__ W,
                                                      const float* __restrict__ cosb,
                                                      const float* __restrict__ sinb,
                                                      u16* __restrict__ qb16,
                                                      u16* __restrict__ kpack,
                                                      u16* __restrict__ vpack,
                                                      float qscale) {
    const int K = K_DIM;
    __shared__ __align__(16) u16 As[128 * 64];
    __shared__ __align__(16) u16 Bs[128 * 64];
    const int tid = threadIdx.x;
    const int lane = tid & 63;
    const int wv = tid >> 6;
    const int wr = wv >> 1;
    const int wc = wv & 1;
    const int cl = lane & 15;
    const int g = lane >> 4;
    const int bm = blockIdx.y * 128;
    const int bn = blockIdx.x * 128;

    const char* Ab = (const char*)A;
    const char* Wb = (const char*)W;

    size_t a_src[4], b_src[4];
    int dst[4];
#pragma unroll
    for (int is = 0; is < 4; ++is) {
        int b = is * 4096 + tid * 16;
        int row = b >> 7;
        int wi = b & 127;
        dst[is] = b;
        a_src[is] = (size_t)(bm + row) * (K * 2) + (wi ^ ((row & 7) << 4));
        b_src[is] = (size_t)(bn + row) * (K * 2) + (wi ^ ((row & 7) << 4));
    }

    f32x4 acc[4][4];
#pragma unroll
    for (int mi = 0; mi < 4; ++mi)
#pragma unroll
        for (int ni = 0; ni < 4; ++ni) acc[mi][ni] = (f32x4){0.f, 0.f, 0.f, 0.f};

    for (int k0b = 0; k0b < K * 2; k0b += 128) {
#pragma unroll
        for (int is = 0; is < 4; ++is)
            GLOAD16(Ab + a_src[is] + k0b, (char*)As + dst[is]);
#pragma unroll
        for (int is = 0; is < 4; ++is)
            GLOAD16(Wb + b_src[is] + k0b, (char*)Bs + dst[is]);
        __syncthreads();
#pragma unroll
        for (int kk = 0; kk < 2; ++kk) {
            const int co = (kk * 64 + g * 16) ^ ((cl & 7) << 4);
            bf16x8 af[4], bfr[4];
#pragma unroll
            for (int mi = 0; mi < 4; ++mi)
                af[mi] = *(const bf16x8*)((const char*)As + (wr * 64 + mi * 16 + cl) * 128 + co);
#pragma unroll
            for (int ni = 0; ni < 4; ++ni)
                bfr[ni] = *(const bf16x8*)((const char*)Bs + (wc * 64 + ni * 16 + cl) * 128 + co);
#pragma unroll
            for (int mi = 0; mi < 4; ++mi)
#pragma unroll
                for (int ni = 0; ni < 4; ++ni)
                    acc[mi][ni] = __builtin_amdgcn_mfma_f32_16x16x32_bf16(af[mi], bfr[ni], acc[mi][ni], 0, 0, 0);
        }
        __syncthreads();
    }

    if (bn < 1536) {
#pragma unroll
        for (int mi = 0; mi < 4; ++mi)
#pragma unroll
            for (int ni = 0; ni < 4; ++ni)
#pragma unroll
                for (int r = 0; r < 4; ++r) {
                    int trow = bm + wr * 64 + mi * 16 + 4 * g + r;
                    int c = bn + wc * 64 + ni * 16 + cl;
                    float v = acc[mi][ni][r];
                    float pv = __shfl_xor(v, 1, 64);
                    int i = (c & 31) >> 1;
                    float cs = cosb[trow * 16 + i];
                    float sn = sinb[trow * 16 + i];
                    float o = v * cs + ((c & 1) ? pv * sn : -pv * sn);
                    qb16[(size_t)trow * E_DIM + c] = f2bf(o * qscale);
                }
    } else if (bn < 2304) {
#pragma unroll
        for (int mi = 0; mi < 4; ++mi)
#pragma unroll
            for (int ni = 0; ni < 4; ++ni)
#pragma unroll
                for (int r = 0; r < 4; ++r) {
                    int trow = bm + wr * 64 + mi * 16 + 4 * g + r;
                    int c = bn + wc * 64 + ni * 16 + cl;
                    float v = acc[mi][ni][r];
                    float pv = __shfl_xor(v, 1, 64);
                    int i = (c & 31) >> 1;
                    float cs = cosb[trow * 16 + i];
                    float sn = sinb[trow * 16 + i];
                    float o = v * cs + ((c & 1) ? pv * sn : -pv * sn);
                    int ck = c - 1536;
                    int m = ck >> 8;
                    int rem = ck & 255;
                    int kvhh = rem >> 5;
                    int d = rem & 31;
                    int cch = trow >> 5, st2 = (trow >> 4) & 1, colk = trow & 15;
                    size_t dstb = ((((size_t)(kvhh * 64 + cch) * 3 + m) * 2 + st2) * 16 + colk) * 32 + d;
                    kpack[dstb] = f2bf(o);
                }
    } else {
#pragma unroll
        for (int mi = 0; mi < 4; ++mi)
#pragma unroll
            for (int ni = 0; ni < 4; ++ni)
#pragma unroll
                for (int r = 0; r < 4; ++r) {
                    int trow = bm + wr * 64 + mi * 16 + 4 * g + r;
                    int c = bn + wc * 64 + ni * 16 + cl;
                    int fq = c - 2304;
                    int kvhh = fq / 96;
                    int f = fq - kvhh * 96;
                    size_t dstb = ((size_t)(kvhh * 64 + (trow >> 5)) * 96 + f) * 32 + (trow & 31);
                    vpack[dstb] = f2bf(acc[mi][ni][r]);
                }
    }
}

// ---------------- bf16 MFMA GEMM 128x64 tile (output projection, unchanged)
__global__ __launch_bounds__(256) void gemm_mfma_out(const u16* __restrict__ A,
                                                     const u16* __restrict__ W,
                                                     float* __restrict__ Cp,
                                                     int K, int ldC) {
    __shared__ __align__(16) u16 As[128 * 64];
    __shared__ __align__(16) u16 Bs[64 * 64];
    const int tid = threadIdx.x;
    const int lane = tid & 63;
    const int wv = tid >> 6;
    const int wr = wv >> 1;
    const int wc = wv & 1;
    const int cl = lane & 15;
    const int g = lane >> 4;
    const int bm = blockIdx.y * 128;
    const int bn = blockIdx.x * 64;

    const char* Ab = (const char*)A;
    const char* Wb = (const char*)W;

    size_t a_src[4];
    int a_dst[4];
#pragma unroll
    for (int is = 0; is < 4; ++is) {
        int b = is * 4096 + wv * 1024 + lane * 16;
        int row = b >> 7;
        int wi = b & 127;
        a_src[is] = (size_t)(bm + row) * (K * 2) + (wi ^ ((row & 7) << 4));
        a_dst[is] = b;
    }
    size_t b_src[2];
    int b_dst[2];
#pragma unroll
    for (int is = 0; is < 2; ++is) {
        int b = is * 4096 + wv * 1024 + lane * 16;
        int row = b >> 7;
        int wi = b & 127;
        b_src[is] = (size_t)(bn + row) * (K * 2) + (wi ^ ((row & 7) << 4));
        b_dst[is] = b;
    }

    f32x4 acc[4][2];
#pragma unroll
    for (int mi = 0; mi < 4; ++mi)
#pragma unroll
        for (int ni = 0; ni < 2; ++ni) acc[mi][ni] = (f32x4){0.f, 0.f, 0.f, 0.f};

    for (int k0b = 0; k0b < K * 2; k0b += 128) {
#pragma unroll
        for (int is = 0; is < 4; ++is)
            GLOAD16(Ab + a_src[is] + k0b, (char*)As + a_dst[is]);
#pragma unroll
        for (int is = 0; is < 2; ++is)
            GLOAD16(Wb + b_src[is] + k0b, (char*)Bs + b_dst[is]);
        __syncthreads();
#pragma unroll
        for (int kk = 0; kk < 2; ++kk) {
            const int co = (kk * 64 + g * 16) ^ ((cl & 7) << 4);
            bf16x8 af[4], bfr[2];
#pragma unroll
            for (int mi = 0; mi < 4; ++mi)
                af[mi] = *(const bf16x8*)((const char*)As + (wr * 64 + mi * 16 + cl) * 128 + co);
#pragma unroll
            for (int ni = 0; ni < 2; ++ni)
                bfr[ni] = *(const bf16x8*)((const char*)Bs + (wc * 32 + ni * 16 + cl) * 128 + co);
#pragma unroll
            for (int mi = 0; mi < 4; ++mi)
#pragma unroll
                for (int ni = 0; ni < 2; ++ni)
                    acc[mi][ni] = __builtin_amdgcn_mfma_f32_16x16x32_bf16(af[mi], bfr[ni], acc[mi][ni], 0, 0, 0);
        }
        __syncthreads();
    }

#pragma unroll
    for (int mi = 0; mi < 4; ++mi)
#pragma unroll
        for (int ni = 0; ni < 2; ++ni)
#pragma unroll
            for (int r = 0; r < 4; ++r) {
                size_t row = bm + wr * 64 + mi * 16 + 4 * g + r;
                size_t col = bn + wc * 32 + ni * 16 + cl;
                Cp[row * ldC + col] = acc[mi][ni][r];
            }
}

// ---------------- Single-pass attention: per-ensemble waves.
// 6 waves/block (3 ensembles x 2 key-split). Each wave sweeps keys ONCE computing
// unnormalized O_m = sum exp2(S_m) V and l_m together (exp computed once). Epilogue:
// fac_m = tanh(raw_m)*wscale / l_m, O = sum_m fac_m O_m, then RMS + subln.
// 1024 blocks x 6 waves oversubscribes CUs -> backfill queue -> LPT order works.
__global__ __launch_bounds__(384) void attn_one(const u16* __restrict__ qb,
                                                const u16* __restrict__ kpack,
                                                const u16* __restrict__ vpack,
                                                const float* __restrict__ raw_map,
                                                const float* __restrict__ wscale,
                                                const float* __restrict__ subln,
                                                u16* __restrict__ outb) {
    // smem union: plds [6][2][16][48]u16 = 18432 B (main loop)
    //             red1 [6][2][16]f32 = 768 B; redA 3 regions x 12288 B = 36864 B (epilogue)
    __shared__ __align__(16) char smem[36864];
    const int tid = threadIdx.x;
    const int lane = tid & 63;
    const int wv = tid >> 6;          // 0..5
    const int m = wv >> 1;            // ensemble
    const int ks = wv & 1;            // key-split half
    const int col = lane & 15;
    const int g = lane >> 4;
    const int lid = blockIdx.y * 64 + blockIdx.x;
    const int kvh = lid & 7;          // XCD affinity
    const int rest = lid >> 3;
    const int h = kvh * 2 + (rest & 1);
    const int qt = 63 - (rest >> 1);  // LPT: heaviest first
    const int qbase = qt * 32;
    const int nfull = qt;             // mask-free chunks

    u16 (*plds)[2][16][48] = (u16(*)[2][16][48])smem;
    float (*red1)[2][16] = (float(*)[2][16])smem;

    bf16x8 qfrag[2];
#pragma unroll
    for (int q2 = 0; q2 < 2; ++q2)
        qfrag[q2] = *(const bf16x8*)(qb + (size_t)(qbase + 16 * q2 + col) * E_DIM + m * 512 + h * 32 + 8 * g);

    f32x4 oacc[2][6];
#pragma unroll
    for (int q2 = 0; q2 < 2; ++q2)
#pragma unroll
        for (int ft = 0; ft < 6; ++ft) oacc[q2][ft] = (f32x4){0.f, 0.f, 0.f, 0.f};
    float lsum[2] = {0.f, 0.f};

    const int laneoff = col * 32 + 8 * g;
    const u16* kt = kpack + ((size_t)(kvh * 64 + ks) * 3 + m) * 1024 + laneoff;
    const u16* vt = vpack + (size_t)(kvh * 64 + ks) * 3072 + laneoff;

    for (int c = ks; c < nfull; c += 2) {
        bf16x8 kf0 = *(const bf16x8*)(kt);
        bf16x8 kf1 = *(const bf16x8*)(kt + 512);
        bf16x8 vf[6];
#pragma unroll
        for (int u = 0; u < 6; ++u) vf[u] = *(const bf16x8*)(vt + u * 512);
        kt += 2 * 3072;
        vt += 2 * 3072;

        __builtin_amdgcn_s_setprio(1);
#pragma unroll
        for (int q2 = 0; q2 < 2; ++q2) {
            f32x4 sv0 = __builtin_amdgcn_mfma_f32_16x16x32_bf16(kf0, qfrag[q2], (f32x4){0.f, 0.f, 0.f, 0.f}, 0, 0, 0);
            f32x4 sv1 = __builtin_amdgcn_mfma_f32_16x16x32_bf16(kf1, qfrag[q2], (f32x4){0.f, 0.f, 0.f, 0.f}, 0, 0, 0);
            float p0 = __builtin_amdgcn_exp2f(sv0[0]);
            float p1 = __builtin_amdgcn_exp2f(sv0[1]);
            float p2 = __builtin_amdgcn_exp2f(sv0[2]);
            float p3 = __builtin_amdgcn_exp2f(sv0[3]);
            float p4 = __builtin_amdgcn_exp2f(sv1[0]);
            float p5 = __builtin_amdgcn_exp2f(sv1[1]);
            float p6 = __builtin_amdgcn_exp2f(sv1[2]);
            float p7 = __builtin_amdgcn_exp2f(sv1[3]);
            lsum[q2] += ((p0 + p1) + (p2 + p3)) + ((p4 + p5) + (p6 + p7));
            __hip_bfloat162 a01 = __float22bfloat162_rn(make_float2(p0, p1));
            __hip_bfloat162 a23 = __float22bfloat162_rn(make_float2(p2, p3));
            __hip_bfloat162 b01 = __float22bfloat162_rn(make_float2(p4, p5));
            __hip_bfloat162 b23 = __float22bfloat162_rn(make_float2(p6, p7));
            uint2 w0, w1;
            w0.x = *(u32*)&a01; w0.y = *(u32*)&a23;
            w1.x = *(u32*)&b01; w1.y = *(u32*)&b23;
            *(uint2*)&plds[wv][q2][col][4 * g] = w0;
            *(uint2*)&plds[wv][q2][col][16 + 4 * g] = w1;
        }
#pragma unroll
        for (int q2 = 0; q2 < 2; ++q2) {
            bf16x8 pf = *(const bf16x8*)&plds[wv][q2][col][8 * g];
#pragma unroll
            for (int ft = 0; ft < 6; ++ft)
                oacc[q2][ft] = __builtin_amdgcn_mfma_f32_16x16x32_bf16(pf, vf[ft], oacc[q2][ft], 0, 0, 0);
        }
        __builtin_amdgcn_s_setprio(0);
    }

    // boundary chunk (causal): q2=0 -> st0 triangular, st1 zero; q2=1 -> st0 full, st1 triangular.
    if ((nfull & 1) == ks) {
        const u16* ktm = kpack + ((size_t)(kvh * 64 + nfull) * 3 + m) * 1024 + laneoff;
        const u16* vtm = vpack + (size_t)(kvh * 64 + nfull) * 3072 + laneoff;
        bf16x8 kf0 = *(const bf16x8*)(ktm);
        bf16x8 kf1 = *(const bf16x8*)(ktm + 512);
        bf16x8 vf[6];
#pragma unroll
        for (int u = 0; u < 6; ++u) vf[u] = *(const bf16x8*)(vtm + u * 512);

        {   // q2 = 0
            f32x4 sv = __builtin_amdgcn_mfma_f32_16x16x32_bf16(kf0, qfrag[0], (f32x4){0.f, 0.f, 0.f, 0.f}, 0, 0, 0);
            float p[4];
#pragma unroll
            for (int r = 0; r < 4; ++r) {
                float x = (4 * g + r > col) ? -1e30f : sv[r];
                p[r] = __builtin_amdgcn_exp2f(x);
                lsum[0] += p[r];
            }
            __hip_bfloat162 a01 = __float22bfloat162_rn(make_float2(p[0], p[1]));
            __hip_bfloat162 a23 = __float22bfloat162_rn(make_float2(p[2], p[3]));
            uint2 w0;
            w0.x = *(u32*)&a01; w0.y = *(u32*)&a23;
            *(uint2*)&plds[wv][0][col][4 * g] = w0;
            uint2 z = make_uint2(0u, 0u);
            *(uint2*)&plds[wv][0][col][16 + 4 * g] = z;
        }
        {   // q2 = 1
            f32x4 sv0 = __builtin_amdgcn_mfma_f32_16x16x32_bf16(kf0, qfrag[1], (f32x4){0.f, 0.f, 0.f, 0.f}, 0, 0, 0);
            f32x4 sv1 = __builtin_amdgcn_mfma_f32_16x16x32_bf16(kf1, qfrag[1], (f32x4){0.f, 0.f, 0.f, 0.f}, 0, 0, 0);
            float p0[4], p1[4];
#pragma unroll
            for (int r = 0; r < 4; ++r) {
                p0[r] = __builtin_amdgcn_exp2f(sv0[r]);
                float x = (4 * g + r > col) ? -1e30f : sv1[r];
                p1[r] = __builtin_amdgcn_exp2f(x);
                lsum[1] += p0[r] + p1[r];
            }
            __hip_bfloat162 a01 = __float22bfloat162_rn(make_float2(p0[0], p0[1]));
            __hip_bfloat162 a23 = __float22bfloat162_rn(make_float2(p0[2], p0[3]));
            __hip_bfloat162 b01 = __float22bfloat162_rn(make_float2(p1[0], p1[1]));
            __hip_bfloat162 b23 = __float22bfloat162_rn(make_float2(p1[2], p1[3]));
            uint2 w0, w1;
            w0.x = *(u32*)&a01; w0.y = *(u32*)&a23;
            w1.x = *(u32*)&b01; w1.y = *(u32*)&b23;
            *(uint2*)&plds[wv][1][col][4 * g] = w0;
            *(uint2*)&plds[wv][1][col][16 + 4 * g] = w1;
        }
#pragma unroll
        for (int q2 = 0; q2 < 2; ++q2) {
            bf16x8 pf = *(const bf16x8*)&plds[wv][q2][col][8 * g];
#pragma unroll
            for (int ft = 0; ft < 6; ++ft)
                oacc[q2][ft] = __builtin_amdgcn_mfma_f32_16x16x32_bf16(pf, vf[ft], oacc[q2][ft], 0, 0, 0);
        }
    }

    // ---- lsum full reduce within wave (sum over 16-lane groups)
#pragma unroll
    for (int q2 = 0; q2 < 2; ++q2) {
        lsum[q2] += __shfl_xor(lsum[q2], 16, 64);
        lsum[q2] += __shfl_xor(lsum[q2], 32, 64);
    }
    __syncthreads();   // plds dead
    if (g == 0) {
#pragma unroll
        for (int q2 = 0; q2 < 2; ++q2) red1[wv][q2][col] = lsum[q2];
    }
    __syncthreads();

    // fac per q-row (row = 4g+r in oacc layout), scale this wave's oacc by fac_m
    {
        float mwm = tanhf(raw_map[m]) * wscale[0];
#pragma unroll
        for (int q2 = 0; q2 < 2; ++q2)
#pragma unroll
            for (int r = 0; r < 4; ++r) {
                float tot = red1[2 * m][q2][4 * g + r] + red1[2 * m + 1][q2][4 * g + r];
                float f = mwm / tot;
                oacc[q2][0][r] *= f; oacc[q2][1][r] *= f; oacc[q2][2][r] *= f;
                oacc[q2][3][r] *= f; oacc[q2][4][r] *= f; oacc[q2][5][r] *= f;
            }
    }
    __syncthreads();   // red1 dead; redA takes over

    float* redA = (float*)smem;   // 3 regions x [64][48] f32
    // round A: waves 3,4,5 -> regions 0,1,2; waves 0,1,2 accumulate
    if (wv >= 3) {
        float4* rp = (float4*)(redA + (size_t)(wv - 3) * 3072 + (size_t)lane * 48);
#pragma unroll
        for (int q2 = 0; q2 < 2; ++q2)
#pragma unroll
            for (int ft = 0; ft < 6; ++ft)
                rp[q2 * 6 + ft] = make_float4(oacc[q2][ft][0], oacc[q2][ft][1], oacc[q2][ft][2], oacc[q2][ft][3]);
    }
    __syncthreads();
    if (wv < 3) {
        const float4* rp = (const float4*)(redA + (size_t)wv * 3072 + (size_t)lane * 48);
#pragma unroll
        for (int q2 = 0; q2 < 2; ++q2)
#pragma unroll
            for (int ft = 0; ft < 6; ++ft) {
                float4 a = rp[q2 * 6 + ft];
                oacc[q2][ft][0] += a.x; oacc[q2][ft][1] += a.y;
                oacc[q2][ft][2] += a.z; oacc[q2][ft][3] += a.w;
            }
    }
    __syncthreads();
    // round B: waves 1,2 -> regions 0,1; wave 0 accumulates both
    if (wv == 1 || wv == 2) {
        float4* rp = (float4*)(redA + (size_t)(wv - 1) * 3072 + (size_t)lane * 48);
#pragma unroll
        for (int q2 = 0; q2 < 2; ++q2)
#pragma unroll
            for (int ft = 0; ft < 6; ++ft)
                rp[q2 * 6 + ft] = make_float4(oacc[q2][ft][0], oacc[q2][ft][1], oacc[q2][ft][2], oacc[q2][ft][3]);
    }
    __syncthreads();
    if (wv != 0) return;
#pragma unroll
    for (int s2 = 0; s2 < 2; ++s2) {
        const float4* rp = (const float4*)(redA + (size_t)s2 * 3072 + (size_t)lane * 48);
#pragma unroll
        for (int q2 = 0; q2 < 2; ++q2)
#pragma unroll
            for (int ft = 0; ft < 6; ++ft) {
                float4 a = rp[q2 * 6 + ft];
                oacc[q2][ft][0] += a.x; oacc[q2][ft][1] += a.y;
                oacc[q2][ft][2] += a.z; oacc[q2][ft][3] += a.w;
            }
    }

    // ---- epilogue (wave 0): RMS + subln
    float ss[2][4] = {{0.f, 0.f, 0.f, 0.f}, {0.f, 0.f, 0.f, 0.f}};
#pragma unroll
    for (int q2 = 0; q2 < 2; ++q2)
#pragma unroll
        for (int ft = 0; ft < 6; ++ft)
#pragma unroll
            for (int r = 0; r < 4; ++r) ss[q2][r] += oacc[q2][ft][r] * oacc[q2][ft][r];
#pragma unroll
    for (int q2 = 0; q2 < 2; ++q2)
#pragma unroll
        for (int r = 0; r < 4; ++r) {
            ss[q2][r] += __shfl_xor(ss[q2][r], 1, 64);
            ss[q2][r] += __shfl_xor(ss[q2][r], 2, 64);
            ss[q2][r] += __shfl_xor(ss[q2][r], 4, 64);
            ss[q2][r] += __shfl_xor(ss[q2][r], 8, 64);
            ss[q2][r] = rsqrtf(ss[q2][r] * (1.f / 96.f) + 1e-5f);
        }
#pragma unroll
    for (int ft = 0; ft < 6; ++ft) {
        float sl = subln[ft * 16 + col];
#pragma unroll
        for (int q2 = 0; q2 < 2; ++q2)
#pragma unroll
            for (int r = 0; r < 4; ++r) {
                int trow = qbase + 16 * q2 + 4 * g + r;
                outb[(size_t)trow * E_DIM + h * 96 + ft * 16 + col] = f2bf(oacc[q2][ft][r] * ss[q2][r] * sl);
            }
    }
}

extern "C" void kernel_launch(void* const* d_in, const int* in_sizes, int n_in,
                              void* d_out, int out_size, void* d_ws, size_t ws_size,
                              hipStream_t stream) {
    const float* x       = (const float*)d_in[0];
    const float* cosb    = (const float*)d_in[1];
    const float* sinb    = (const float*)d_in[2];
    const float* q_w     = (const float*)d_in[3];
    const float* k_w     = (const float*)d_in[4];
    const float* v_w     = (const float*)d_in[5];
    const float* out_w   = (const float*)d_in[6];
    const float* raw_map = (const float*)d_in[7];
    const float* wscale  = (const float*)d_in[8];
    const float* subln   = (const float*)d_in[9];
    float* out = (float*)d_out;

    char* ws = (char*)d_ws;
    u16* xb16   = (u16*)(ws);                    // 2048x1536  (6,291,456 B)  [ab16 alias later]
    u16* wqkv16 = (u16*)(ws + 6291456);          // 3072x1536  (9,437,184 B)
    u16* qb16   = (u16*)(ws + 15728640);         // 2048x1536  (6,291,456 B)
    u16* kpack  = (u16*)(ws + 22020096);         // 8x64x3x2x16x32 (3,145,728 B) + pad
    u16* vpack  = (u16*)(ws + 25190400);         // 8x64x96x32     (3,145,728 B) + pad
    u16* wout16 = (u16*)(ws + 28360704);         // 1536x1536  (4,718,592 B)
    u16* ab16   = xb16;                          // alias: x dead after QKV gemm

    // all f32 -> bf16 conversions in one launch
    cvt_bf16_5<<<9984, 256, 0, stream>>>(x, xb16,
                                         q_w, wqkv16,
                                         k_w, wqkv16 + 2359296,
                                         v_w, wqkv16 + 3538944,
                                         out_w, wout16);

    // fused QKV projection + RoPE + pack (128x128 tile). Q gets hd^-0.5*log2e folded.
    const float qscale = 0.17677669529663687f * 1.4426950408889634f;
    gemm_qkv_fused<<<dim3(3072 / 128, T_DIM / 128), 256, 0, stream>>>(
        xb16, wqkv16, cosb, sinb, qb16, kpack, vpack, qscale);

    // single-pass attention (per-ensemble waves) + combine + RMS + subln -> bf16
    attn_one<<<dim3(64, 16), 384, 0, stream>>>(qb16, kpack, vpack, raw_map, wscale, subln, ab16);

    // output projection: [2048,1536] x [1536,1536]^T -> f32 d_out
    gemm_mfma_out<<<dim3(E_DIM / 64, T_DIM / 128), 256, 0, stream>>>(ab16, wout16, out, K_DIM, E_DIM);
}

// Round 17
// 128.087 us; speedup vs baseline: 1.0439x; 1.0439x over previous
//
#include <hip/hip_runtime.h>
#include <hip/hip_bf16.h>
#include <math.h>

#define T_DIM 2048
#define E_DIM 1536
#define K_DIM 1536

typedef unsigned short u16;
typedef unsigned int u32;
typedef __attribute__((ext_vector_type(8))) short bf16x8;
typedef __attribute__((ext_vector_type(4))) float f32x4;

__device__ __forceinline__ u16 f2bf(float x) {
    unsigned u = __float_as_uint(x);
    return (u16)((u + 0x7fffu + ((u >> 16) & 1u)) >> 16);
}

#define GLOAD16(gsrc, ldst)                                                              \
    __builtin_amdgcn_global_load_lds((const __attribute__((address_space(1))) u32*)(gsrc), \
                                     (__attribute__((address_space(3))) u32*)(ldst), 16, 0, 0)

// ---------------- all f32 -> bf16 conversions in ONE kernel (5 segments)
__global__ __launch_bounds__(256) void cvt_bf16_5(const float* __restrict__ s0, u16* __restrict__ d0,
                                                  const float* __restrict__ s1, u16* __restrict__ d1,
                                                  const float* __restrict__ s2, u16* __restrict__ d2,
                                                  const float* __restrict__ s3, u16* __restrict__ d3,
                                                  const float* __restrict__ s4, u16* __restrict__ d4) {
    int i = blockIdx.x * 256 + threadIdx.x;
    const float* s;
    u16* d;
    int off;
    if (i < 786432)       { s = s0; d = d0; off = i; }
    else if (i < 1376256) { s = s1; d = d1; off = i - 786432; }
    else if (i < 1671168) { s = s2; d = d2; off = i - 1376256; }
    else if (i < 1966080) { s = s3; d = d3; off = i - 1671168; }
    else                  { s = s4; d = d4; off = i - 1966080; }
    float4 v = ((const float4*)s)[off];
    ((ushort4*)d)[off] = make_ushort4(f2bf(v.x), f2bf(v.y), f2bf(v.z), f2bf(v.w));
}

// ---------------- fused QKV GEMM, 128x128 tile, RoPE/pack epilogue (unchanged)
__global__ __launch_bounds__(256) void gemm_qkv_fused(const u16* __restrict__ A,
                                                      const u16* __restrict__ W,
                                                      const float* __restrict__ cosb,
                                                      const float* __restrict__ sinb,
                                                      u16* __restrict__ qb16,
                                                      u16* __restrict__ kpack,
                                                      u16* __restrict__ vpack,
                                                      float qscale) {
    const int K = K_DIM;
    __shared__ __align__(16) u16 As[128 * 64];
    __shared__ __align__(16) u16 Bs[128 * 64];
    const int tid = threadIdx.x;
    const int lane = tid & 63;
    const int wv = tid >> 6;
    const int wr = wv >> 1;
    const int wc = wv & 1;
    const int cl = lane & 15;
    const int g = lane >> 4;
    const int bm = blockIdx.y * 128;
    const int bn = blockIdx.x * 128;

    const char* Ab = (const char*)A;
    const char* Wb = (const char*)W;

    size_t a_src[4], b_src[4];
    int dst[4];
#pragma unroll
    for (int is = 0; is < 4; ++is) {
        int b = is * 4096 + tid * 16;
        int row = b >> 7;
        int wi = b & 127;
        dst[is] = b;
        a_src[is] = (size_t)(bm + row) * (K * 2) + (wi ^ ((row & 7) << 4));
        b_src[is] = (size_t)(bn + row) * (K * 2) + (wi ^ ((row & 7) << 4));
    }

    f32x4 acc[4][4];
#pragma unroll
    for (int mi = 0; mi < 4; ++mi)
#pragma unroll
        for (int ni = 0; ni < 4; ++ni) acc[mi][ni] = (f32x4){0.f, 0.f, 0.f, 0.f};

    for (int k0b = 0; k0b < K * 2; k0b += 128) {
#pragma unroll
        for (int is = 0; is < 4; ++is)
            GLOAD16(Ab + a_src[is] + k0b, (char*)As + dst[is]);
#pragma unroll
        for (int is = 0; is < 4; ++is)
            GLOAD16(Wb + b_src[is] + k0b, (char*)Bs + dst[is]);
        __syncthreads();
#pragma unroll
        for (int kk = 0; kk < 2; ++kk) {
            const int co = (kk * 64 + g * 16) ^ ((cl & 7) << 4);
            bf16x8 af[4], bfr[4];
#pragma unroll
            for (int mi = 0; mi < 4; ++mi)
                af[mi] = *(const bf16x8*)((const char*)As + (wr * 64 + mi * 16 + cl) * 128 + co);
#pragma unroll
            for (int ni = 0; ni < 4; ++ni)
                bfr[ni] = *(const bf16x8*)((const char*)Bs + (wc * 64 + ni * 16 + cl) * 128 + co);
#pragma unroll
            for (int mi = 0; mi < 4; ++mi)
#pragma unroll
                for (int ni = 0; ni < 4; ++ni)
                    acc[mi][ni] = __builtin_amdgcn_mfma_f32_16x16x32_bf16(af[mi], bfr[ni], acc[mi][ni], 0, 0, 0);
        }
        __syncthreads();
    }

    if (bn < 1536) {
#pragma unroll
        for (int mi = 0; mi < 4; ++mi)
#pragma unroll
            for (int ni = 0; ni < 4; ++ni)
#pragma unroll
                for (int r = 0; r < 4; ++r) {
                    int trow = bm + wr * 64 + mi * 16 + 4 * g + r;
                    int c = bn + wc * 64 + ni * 16 + cl;
                    float v = acc[mi][ni][r];
                    float pv = __shfl_xor(v, 1, 64);
                    int i = (c & 31) >> 1;
                    float cs = cosb[trow * 16 + i];
                    float sn = sinb[trow * 16 + i];
                    float o = v * cs + ((c & 1) ? pv * sn : -pv * sn);
                    qb16[(size_t)trow * E_DIM + c] = f2bf(o * qscale);
                }
    } else if (bn < 2304) {
#pragma unroll
        for (int mi = 0; mi < 4; ++mi)
#pragma unroll
            for (int ni = 0; ni < 4; ++ni)
#pragma unroll
                for (int r = 0; r < 4; ++r) {
                    int trow = bm + wr * 64 + mi * 16 + 4 * g + r;
                    int c = bn + wc * 64 + ni * 16 + cl;
                    float v = acc[mi][ni][r];
                    float pv = __shfl_xor(v, 1, 64);
                    int i = (c & 31) >> 1;
                    float cs = cosb[trow * 16 + i];
                    float sn = sinb[trow * 16 + i];
                    float o = v * cs + ((c & 1) ? pv * sn : -pv * sn);
                    int ck = c - 1536;
                    int m = ck >> 8;
                    int rem = ck & 255;
                    int kvhh = rem >> 5;
                    int d = rem & 31;
                    int cch = trow >> 5, st2 = (trow >> 4) & 1, colk = trow & 15;
                    size_t dstb = ((((size_t)(kvhh * 64 + cch) * 3 + m) * 2 + st2) * 16 + colk) * 32 + d;
                    kpack[dstb] = f2bf(o);
                }
    } else {
#pragma unroll
        for (int mi = 0; mi < 4; ++mi)
#pragma unroll
            for (int ni = 0; ni < 4; ++ni)
#pragma unroll
                for (int r = 0; r < 4; ++r) {
                    int trow = bm + wr * 64 + mi * 16 + 4 * g + r;
                    int c = bn + wc * 64 + ni * 16 + cl;
                    int fq = c - 2304;
                    int kvhh = fq / 96;
                    int f = fq - kvhh * 96;
                    size_t dstb = ((size_t)(kvhh * 64 + (trow >> 5)) * 96 + f) * 32 + (trow & 31);
                    vpack[dstb] = f2bf(acc[mi][ni][r]);
                }
    }
}

// ---------------- bf16 MFMA GEMM 128x64 tile (output projection, unchanged)
__global__ __launch_bounds__(256) void gemm_mfma_out(const u16* __restrict__ A,
                                                     const u16* __restrict__ W,
                                                     float* __restrict__ Cp,
                                                     int K, int ldC) {
    __shared__ __align__(16) u16 As[128 * 64];
    __shared__ __align__(16) u16 Bs[64 * 64];
    const int tid = threadIdx.x;
    const int lane = tid & 63;
    const int wv = tid >> 6;
    const int wr = wv >> 1;
    const int wc = wv & 1;
    const int cl = lane & 15;
    const int g = lane >> 4;
    const int bm = blockIdx.y * 128;
    const int bn = blockIdx.x * 64;

    const char* Ab = (const char*)A;
    const char* Wb = (const char*)W;

    size_t a_src[4];
    int a_dst[4];
#pragma unroll
    for (int is = 0; is < 4; ++is) {
        int b = is * 4096 + wv * 1024 + lane * 16;
        int row = b >> 7;
        int wi = b & 127;
        a_src[is] = (size_t)(bm + row) * (K * 2) + (wi ^ ((row & 7) << 4));
        a_dst[is] = b;
    }
    size_t b_src[2];
    int b_dst[2];
#pragma unroll
    for (int is = 0; is < 2; ++is) {
        int b = is * 4096 + wv * 1024 + lane * 16;
        int row = b >> 7;
        int wi = b & 127;
        b_src[is] = (size_t)(bn + row) * (K * 2) + (wi ^ ((row & 7) << 4));
        b_dst[is] = b;
    }

    f32x4 acc[4][2];
#pragma unroll
    for (int mi = 0; mi < 4; ++mi)
#pragma unroll
        for (int ni = 0; ni < 2; ++ni) acc[mi][ni] = (f32x4){0.f, 0.f, 0.f, 0.f};

    for (int k0b = 0; k0b < K * 2; k0b += 128) {
#pragma unroll
        for (int is = 0; is < 4; ++is)
            GLOAD16(Ab + a_src[is] + k0b, (char*)As + a_dst[is]);
#pragma unroll
        for (int is = 0; is < 2; ++is)
            GLOAD16(Wb + b_src[is] + k0b, (char*)Bs + b_dst[is]);
        __syncthreads();
#pragma unroll
        for (int kk = 0; kk < 2; ++kk) {
            const int co = (kk * 64 + g * 16) ^ ((cl & 7) << 4);
            bf16x8 af[4], bfr[2];
#pragma unroll
            for (int mi = 0; mi < 4; ++mi)
                af[mi] = *(const bf16x8*)((const char*)As + (wr * 64 + mi * 16 + cl) * 128 + co);
#pragma unroll
            for (int ni = 0; ni < 2; ++ni)
                bfr[ni] = *(const bf16x8*)((const char*)Bs + (wc * 32 + ni * 16 + cl) * 128 + co);
#pragma unroll
            for (int mi = 0; mi < 4; ++mi)
#pragma unroll
                for (int ni = 0; ni < 2; ++ni)
                    acc[mi][ni] = __builtin_amdgcn_mfma_f32_16x16x32_bf16(af[mi], bfr[ni], acc[mi][ni], 0, 0, 0);
        }
        __syncthreads();
    }

#pragma unroll
    for (int mi = 0; mi < 4; ++mi)
#pragma unroll
        for (int ni = 0; ni < 2; ++ni)
#pragma unroll
            for (int r = 0; r < 4; ++r) {
                size_t row = bm + wr * 64 + mi * 16 + 4 * g + r;
                size_t col = bn + wc * 32 + ni * 16 + cl;
                Cp[row * ldC + col] = acc[mi][ni][r];
            }
}

// ---------------- Fused single-pass attention: lsum + PV in ONE kernel, ONE qt/block.
// 1024 blocks x 4 waves: restores r11's 4 blocks/CU occupancy while keeping r12's
// fusion savings (no lsum launch, no facbuf round-trip). XCD affinity lid%8==kvh,
// LPT heaviest-first within each (kvh,h).
__global__ __launch_bounds__(256) void attn_fused(const u16* __restrict__ qb,
                                                  const u16* __restrict__ kpack,
                                                  const u16* __restrict__ vpack,
                                                  const float* __restrict__ raw_map,
                                                  const float* __restrict__ wscale,
                                                  const float* __restrict__ subln,
                                                  u16* __restrict__ outb) {
    __shared__ __align__(16) char smem[12288];   // union: plds 10240 / red1 1536 / red2 12288
    const int tid = threadIdx.x;
    const int lane = tid & 63;
    const int wv = tid >> 6;
    const int col = lane & 15;
    const int g = lane >> 4;
    const int lid = blockIdx.y * 64 + blockIdx.x;
    const int kvh = lid & 7;
    const int rest = lid >> 3;
    const int h = kvh * 2 + (rest & 1);
    const int qt = 63 - (rest >> 1);          // LPT
    const int qbase = qt * 32;
    const int nfull = qt;

    u16 (*plds)[2][16][40] = (u16(*)[2][16][40])smem;
    float (*red1)[3][2][16] = (float(*)[3][2][16])smem;
    float (*red2)[48] = (float(*)[48])smem;

    bf16x8 qfrag[3][2];
#pragma unroll
    for (int m = 0; m < 3; ++m)
#pragma unroll
        for (int q2 = 0; q2 < 2; ++q2)
            qfrag[m][q2] = *(const bf16x8*)(qb + (size_t)(qbase + 16 * q2 + col) * E_DIM + m * 512 + h * 32 + 8 * g);

    const int laneoff = col * 32 + 8 * g;

    // ================= lsum phase (K only) =================
    float lsum[3][2] = {{0.f, 0.f}, {0.f, 0.f}, {0.f, 0.f}};
    {
        const u16* kt = kpack + (size_t)(kvh * 64 + wv) * 3072;
        for (int c = wv; c < nfull; c += 4) {
            bf16x8 kf[6];
#pragma unroll
            for (int u = 0; u < 6; ++u) kf[u] = *(const bf16x8*)(kt + laneoff + u * 512);
            kt += 4 * 3072;
            __builtin_amdgcn_s_setprio(1);
#pragma unroll
            for (int m = 0; m < 3; ++m)
#pragma unroll
                for (int st = 0; st < 2; ++st)
#pragma unroll
                    for (int q2 = 0; q2 < 2; ++q2) {
                        f32x4 sv = __builtin_amdgcn_mfma_f32_16x16x32_bf16(
                            kf[m * 2 + st], qfrag[m][q2], (f32x4){0.f, 0.f, 0.f, 0.f}, 0, 0, 0);
                        lsum[m][q2] += (__builtin_amdgcn_exp2f(sv[0]) + __builtin_amdgcn_exp2f(sv[1])) +
                                       (__builtin_amdgcn_exp2f(sv[2]) + __builtin_amdgcn_exp2f(sv[3]));
                    }
            __builtin_amdgcn_s_setprio(0);
        }
        if ((nfull & 3) == wv) {
            const u16* ktm = kpack + (size_t)(kvh * 64 + nfull) * 3072 + laneoff;
            bf16x8 kf[6];
#pragma unroll
            for (int u = 0; u < 6; ++u) kf[u] = *(const bf16x8*)(ktm + u * 512);
#pragma unroll
            for (int m = 0; m < 3; ++m) {
                {
                    f32x4 sv = __builtin_amdgcn_mfma_f32_16x16x32_bf16(
                        kf[m * 2 + 0], qfrag[m][0], (f32x4){0.f, 0.f, 0.f, 0.f}, 0, 0, 0);
#pragma unroll
                    for (int r = 0; r < 4; ++r) {
                        float x = (4 * g + r > col) ? -1e30f : sv[r];
                        lsum[m][0] += __builtin_amdgcn_exp2f(x);
                    }
                }
                {
                    f32x4 sv = __builtin_amdgcn_mfma_f32_16x16x32_bf16(
                        kf[m * 2 + 0], qfrag[m][1], (f32x4){0.f, 0.f, 0.f, 0.f}, 0, 0, 0);
                    lsum[m][1] += (__builtin_amdgcn_exp2f(sv[0]) + __builtin_amdgcn_exp2f(sv[1])) +
                                  (__builtin_amdgcn_exp2f(sv[2]) + __builtin_amdgcn_exp2f(sv[3]));
                }
                {
                    f32x4 sv = __builtin_amdgcn_mfma_f32_16x16x32_bf16(
                        kf[m * 2 + 1], qfrag[m][1], (f32x4){0.f, 0.f, 0.f, 0.f}, 0, 0, 0);
#pragma unroll
                    for (int r = 0; r < 4; ++r) {
                        float x = (4 * g + r > col) ? -1e30f : sv[r];
                        lsum[m][1] += __builtin_amdgcn_exp2f(x);
                    }
                }
            }
        }
    }
#pragma unroll
    for (int m = 0; m < 3; ++m)
#pragma unroll
        for (int q2 = 0; q2 < 2; ++q2) {
            lsum[m][q2] += __shfl_xor(lsum[m][q2], 16, 64);
            lsum[m][q2] += __shfl_xor(lsum[m][q2], 32, 64);
        }
    if (g == 0) {
#pragma unroll
        for (int m = 0; m < 3; ++m)
#pragma unroll
            for (int q2 = 0; q2 < 2; ++q2) red1[wv][m][q2][col] = lsum[m][q2];
    }
    __syncthreads();
    float fac[3][2];
    {
        float wsc = wscale[0];
#pragma unroll
        for (int m = 0; m < 3; ++m) {
            float mwm = tanhf(raw_map[m]) * wsc;
#pragma unroll
            for (int q2 = 0; q2 < 2; ++q2)
                fac[m][q2] = mwm / (red1[0][m][q2][col] + red1[1][m][q2][col] +
                                    red1[2][m][q2][col] + red1[3][m][q2][col]);
        }
    }
    __syncthreads();   // red1 dead; plds takes over

    // ================= PV phase =================
    f32x4 oacc[2][6];
#pragma unroll
    for (int q2 = 0; q2 < 2; ++q2)
#pragma unroll
        for (int ft = 0; ft < 6; ++ft) oacc[q2][ft] = (f32x4){0.f, 0.f, 0.f, 0.f};

    {
        const u16* kt = kpack + (size_t)(kvh * 64 + wv) * 3072;
        const u16* vt = vpack + (size_t)(kvh * 64 + wv) * 3072;
        for (int c = wv; c < nfull; c += 4) {
            bf16x8 kf[6], vf[6];
#pragma unroll
            for (int u = 0; u < 6; ++u) kf[u] = *(const bf16x8*)(kt + laneoff + u * 512);
#pragma unroll
            for (int u = 0; u < 6; ++u) vf[u] = *(const bf16x8*)(vt + laneoff + u * 512);
            kt += 4 * 3072;
            vt += 4 * 3072;

            __builtin_amdgcn_s_setprio(1);
#pragma unroll
            for (int q2 = 0; q2 < 2; ++q2)
#pragma unroll
                for (int st = 0; st < 2; ++st) {
                    float pp[4] = {0.f, 0.f, 0.f, 0.f};
#pragma unroll
                    for (int m = 0; m < 3; ++m) {
                        f32x4 sv = __builtin_amdgcn_mfma_f32_16x16x32_bf16(
                            kf[m * 2 + st], qfrag[m][q2], (f32x4){0.f, 0.f, 0.f, 0.f}, 0, 0, 0);
#pragma unroll
                        for (int r = 0; r < 4; ++r)
                            pp[r] += fac[m][q2] * __builtin_amdgcn_exp2f(sv[r]);
                    }
                    __hip_bfloat162 b01 = __float22bfloat162_rn(make_float2(pp[0], pp[1]));
                    __hip_bfloat162 b23 = __float22bfloat162_rn(make_float2(pp[2], pp[3]));
                    uint2 w;
                    w.x = *(u32*)&b01;
                    w.y = *(u32*)&b23;
                    *(uint2*)&plds[wv][q2][col][st * 16 + 4 * g] = w;
                }
#pragma unroll
            for (int q2 = 0; q2 < 2; ++q2) {
                bf16x8 pf = *(const bf16x8*)&plds[wv][q2][col][8 * g];
#pragma unroll
                for (int ft = 0; ft < 6; ++ft)
                    oacc[q2][ft] = __builtin_amdgcn_mfma_f32_16x16x32_bf16(pf, vf[ft], oacc[q2][ft], 0, 0, 0);
            }
            __builtin_amdgcn_s_setprio(0);
        }

        // boundary chunk: q2=0 -> st0 triangular, st1 zeros; q2=1 -> st0 full, st1 triangular.
        if ((nfull & 3) == wv) {
            const u16* ktm = kpack + (size_t)(kvh * 64 + nfull) * 3072 + laneoff;
            const u16* vtm = vpack + (size_t)(kvh * 64 + nfull) * 3072 + laneoff;
            bf16x8 kf[6], vf[6];
#pragma unroll
            for (int u = 0; u < 6; ++u) kf[u] = *(const bf16x8*)(ktm + u * 512);
#pragma unroll
            for (int u = 0; u < 6; ++u) vf[u] = *(const bf16x8*)(vtm + u * 512);

            {
                float pp[4] = {0.f, 0.f, 0.f, 0.f};
#pragma unroll
                for (int m = 0; m < 3; ++m) {
                    f32x4 sv = __builtin_amdgcn_mfma_f32_16x16x32_bf16(
                        kf[m * 2 + 0], qfrag[m][0], (f32x4){0.f, 0.f, 0.f, 0.f}, 0, 0, 0);
#pragma unroll
                    for (int r = 0; r < 4; ++r) {
                        float x = (4 * g + r > col) ? -1e30f : sv[r];
                        pp[r] += fac[m][0] * __builtin_amdgcn_exp2f(x);
                    }
                }
                __hip_bfloat162 b01 = __float22bfloat162_rn(make_float2(pp[0], pp[1]));
                __hip_bfloat162 b23 = __float22bfloat162_rn(make_float2(pp[2], pp[3]));
                uint2 w;
                w.x = *(u32*)&b01;
                w.y = *(u32*)&b23;
                *(uint2*)&plds[wv][0][col][4 * g] = w;
                uint2 z = make_uint2(0u, 0u);
                *(uint2*)&plds[wv][0][col][16 + 4 * g] = z;
            }
            {
                float p0[4] = {0.f, 0.f, 0.f, 0.f};
                float p1[4] = {0.f, 0.f, 0.f, 0.f};
#pragma unroll
                for (int m = 0; m < 3; ++m) {
                    f32x4 sv0 = __builtin_amdgcn_mfma_f32_16x16x32_bf16(
                        kf[m * 2 + 0], qfrag[m][1], (f32x4){0.f, 0.f, 0.f, 0.f}, 0, 0, 0);
                    f32x4 sv1 = __builtin_amdgcn_mfma_f32_16x16x32_bf16(
                        kf[m * 2 + 1], qfrag[m][1], (f32x4){0.f, 0.f, 0.f, 0.f}, 0, 0, 0);
#pragma unroll
                    for (int r = 0; r < 4; ++r) {
                        p0[r] += fac[m][1] * __builtin_amdgcn_exp2f(sv0[r]);
                        float x = (4 * g + r > col) ? -1e30f : sv1[r];
                        p1[r] += fac[m][1] * __builtin_amdgcn_exp2f(x);
                    }
                }
                __hip_bfloat162 a01 = __float22bfloat162_rn(make_float2(p0[0], p0[1]));
                __hip_bfloat162 a23 = __float22bfloat162_rn(make_float2(p0[2], p0[3]));
                uint2 w0;
                w0.x = *(u32*)&a01;
                w0.y = *(u32*)&a23;
                *(uint2*)&plds[wv][1][col][4 * g] = w0;
                __hip_bfloat162 b01 = __float22bfloat162_rn(make_float2(p1[0], p1[1]));
                __hip_bfloat162 b23 = __float22bfloat162_rn(make_float2(p1[2], p1[3]));
                uint2 w1;
                w1.x = *(u32*)&b01;
                w1.y = *(u32*)&b23;
                *(uint2*)&plds[wv][1][col][16 + 4 * g] = w1;
            }
#pragma unroll
            for (int q2 = 0; q2 < 2; ++q2) {
                bf16x8 pf = *(const bf16x8*)&plds[wv][q2][col][8 * g];
#pragma unroll
                for (int ft = 0; ft < 6; ++ft)
                    oacc[q2][ft] = __builtin_amdgcn_mfma_f32_16x16x32_bf16(pf, vf[ft], oacc[q2][ft], 0, 0, 0);
            }
        }
    }

    // ---- cross-wave reduce: sequential rounds through the union buffer
    __syncthreads();   // plds dead; red2 takes over
#pragma unroll
    for (int src = 1; src < 4; ++src) {
        if (wv == src) {
            float4* rp = (float4*)red2[lane];
#pragma unroll
            for (int q2 = 0; q2 < 2; ++q2)
#pragma unroll
                for (int ft = 0; ft < 6; ++ft)
                    rp[q2 * 6 + ft] = make_float4(oacc[q2][ft][0], oacc[q2][ft][1],
                                                  oacc[q2][ft][2], oacc[q2][ft][3]);
        }
        __syncthreads();
        if (wv == 0) {
            const float4* rp = (const float4*)red2[lane];
#pragma unroll
            for (int q2 = 0; q2 < 2; ++q2)
#pragma unroll
                for (int ft = 0; ft < 6; ++ft) {
                    float4 a = rp[q2 * 6 + ft];
                    oacc[q2][ft][0] += a.x; oacc[q2][ft][1] += a.y;
                    oacc[q2][ft][2] += a.z; oacc[q2][ft][3] += a.w;
                }
        }
        __syncthreads();
    }
    if (wv != 0) return;

    // ---- epilogue: RMS + subln (fac already folded into P)
    float ss[2][4] = {{0.f, 0.f, 0.f, 0.f}, {0.f, 0.f, 0.f, 0.f}};
#pragma unroll
    for (int q2 = 0; q2 < 2; ++q2)
#pragma unroll
        for (int ft = 0; ft < 6; ++ft)
#pragma unroll
            for (int r = 0; r < 4; ++r) ss[q2][r] += oacc[q2][ft][r] * oacc[q2][ft][r];
#pragma unroll
    for (int q2 = 0; q2 < 2; ++q2)
#pragma unroll
        for (int r = 0; r < 4; ++r) {
            ss[q2][r] += __shfl_xor(ss[q2][r], 1, 64);
            ss[q2][r] += __shfl_xor(ss[q2][r], 2, 64);
            ss[q2][r] += __shfl_xor(ss[q2][r], 4, 64);
            ss[q2][r] += __shfl_xor(ss[q2][r], 8, 64);
            ss[q2][r] = rsqrtf(ss[q2][r] * (1.f / 96.f) + 1e-5f);
        }
#pragma unroll
    for (int ft = 0; ft < 6; ++ft) {
        float sl = subln[ft * 16 + col];
#pragma unroll
        for (int q2 = 0; q2 < 2; ++q2)
#pragma unroll
            for (int r = 0; r < 4; ++r) {
                int trow = qbase + 16 * q2 + 4 * g + r;
                outb[(size_t)trow * E_DIM + h * 96 + ft * 16 + col] = f2bf(oacc[q2][ft][r] * ss[q2][r] * sl);
            }
    }
}

extern "C" void kernel_launch(void* const* d_in, const int* in_sizes, int n_in,
                              void* d_out, int out_size, void* d_ws, size_t ws_size,
                              hipStream_t stream) {
    const float* x       = (const float*)d_in[0];
    const float* cosb    = (const float*)d_in[1];
    const float* sinb    = (const float*)d_in[2];
    const float* q_w     = (const float*)d_in[3];
    const float* k_w     = (const float*)d_in[4];
    const float* v_w     = (const float*)d_in[5];
    const float* out_w   = (const float*)d_in[6];
    const float* raw_map = (const float*)d_in[7];
    const float* wscale  = (const float*)d_in[8];
    const float* subln   = (const float*)d_in[9];
    float* out = (float*)d_out;

    char* ws = (char*)d_ws;
    u16* xb16   = (u16*)(ws);                    // 2048x1536  (6,291,456 B)  [ab16 alias later]
    u16* wqkv16 = (u16*)(ws + 6291456);          // 3072x1536  (9,437,184 B)
    u16* qb16   = (u16*)(ws + 15728640);         // 2048x1536  (6,291,456 B)
    u16* kpack  = (u16*)(ws + 22020096);         // 8x64x3x2x16x32 (3,145,728 B) + pad
    u16* vpack  = (u16*)(ws + 25190400);         // 8x64x96x32     (3,145,728 B) + pad
    u16* wout16 = (u16*)(ws + 28360704);         // 1536x1536  (4,718,592 B)
    u16* ab16   = xb16;                          // alias: x dead after QKV gemm

    // all f32 -> bf16 conversions in one launch
    cvt_bf16_5<<<9984, 256, 0, stream>>>(x, xb16,
                                         q_w, wqkv16,
                                         k_w, wqkv16 + 2359296,
                                         v_w, wqkv16 + 3538944,
                                         out_w, wout16);

    // fused QKV projection + RoPE + pack (128x128 tile). Q gets hd^-0.5*log2e folded.
    const float qscale = 0.17677669529663687f * 1.4426950408889634f;
    gemm_qkv_fused<<<dim3(3072 / 128, T_DIM / 128), 256, 0, stream>>>(
        xb16, wqkv16, cosb, sinb, qb16, kpack, vpack, qscale);

    // fused attention (lsum + PV + combine + RMS + subln), 1024 blocks x 4 waves
    attn_fused<<<dim3(64, 16), 256, 0, stream>>>(qb16, kpack, vpack, raw_map, wscale, subln, ab16);

    // output projection: [2048,1536] x [1536,1536]^T -> f32 d_out
    gemm_mfma_out<<<dim3(E_DIM / 64, T_DIM / 128), 256, 0, stream>>>(ab16, wout16, out, K_DIM, E_DIM);
}